// Round 3
// baseline (71.171 us; speedup 1.0000x reference)
//
#include <hip/hip_runtime.h>

// Problem constants (fixed by setup_inputs)
#define NG   256   // graphs
#define NPG  64    // nodes per graph
#define INF  128   // in features (K)
#define OUTF 128   // out features (N)
#define NH   16    // heads

// LDS row stride for Wl[n][k] in bf16 units.
// 136 bf16 = 272 B = 68 dwords: rows stay 16B-aligned (ds_read_b128 ok) and
// the b128 B-fragment read (start bank 4*(l16+quad) % 32) spreads the wave's
// 64 lanes x 4 dwords uniformly at 8 dwords/bank = the conflict-free floor.
#define LDSK 136

typedef __attribute__((ext_vector_type(8))) short bf16x8;  // 8 bf16 = 4 VGPRs
typedef __attribute__((ext_vector_type(4))) float f32x4;   // MFMA accumulator

__device__ __forceinline__ unsigned short f2bf(float f) {
    union { float f; unsigned int i; } c; c.f = f;
    unsigned int r = c.i + 0x7fffu + ((c.i >> 16) & 1u);  // round-to-nearest-even
    return (unsigned short)(r >> 16);
}

// One block per graph (grid 256 = 1 block/CU), now 1024 threads = 16 waves
// (4 waves/SIMD, up from 2): more TLP to hide the cold-HBM loads and the
// pre-barrier vmcnt(0) drain of this single-shot kernel.
//
// Wave w: rows (w&3)*16, cols (w>>2)*32 (16x32 tile, nt=0..1).
// Ordering (the optimization, carried from round 2):
//   1. X float4 loads issued FIRST (independent of head).
//   2. W[h] staged -> Wl[n][k] bf16: each thread reads 8 k-strided float2
//      (each instr = one full 512 B W row across the wave, coalesced),
//      writes two ds_write_b128. One iteration now (1024 threads).
//   3. bias loads + A-fragment cvt hoisted ABOVE the barrier (depend only on
//      X/bias, in flight since step 1) -> post-barrier path is ds_read+MFMA.
__global__ __launch_bounds__(1024, 4) void mhl_fused_kernel(
    const float* __restrict__ X,     // [NG*NPG][INF] fp32
    const int*   __restrict__ head,  // [NG]
    const float* __restrict__ W,     // [NH][INF][OUTF] fp32
    const float* __restrict__ bias,  // [NH][OUTF] fp32
    float*       __restrict__ Y)     // [NG*NPG][OUTF] fp32
{
    __shared__ __align__(16) unsigned short Wl[OUTF * LDSK];  // 34816 B

    int g = (int)blockIdx.x;
    int t = (int)threadIdx.x;
    int wave = t >> 6, lane = t & 63;
    int quad = lane >> 4, l16 = lane & 15;
    int mrow = (wave & 3) * 16;    // row tile within graph
    int ncol = (wave >> 2) * 32;   // column quarter

    // ---- 1) Issue X loads up front (in flight during staging + barrier) ----
    const float* Xg = X + (g * NPG + mrow + l16) * INF + quad * 8;
    float4 xv[8];
#pragma unroll
    for (int kt = 0; kt < 4; ++kt) {
        xv[2 * kt]     = *(const float4*)(Xg + kt * 32);
        xv[2 * kt + 1] = *(const float4*)(Xg + kt * 32 + 4);
    }

    int h = head[g];  // uniform -> s_load

    // ---- 2) Stage W[h] -> Wl[n][k] bf16 (one iteration, 1024 threads) ----
    // thread t: column pair n0=2*(t&63), k-chunk k0=8*(t>>6).
    // Loads: j=0..7, W[k0+j][n0..n0+1] -- each instruction covers one full
    // 512 B k-row across the wave's 64 lanes (fully coalesced).
    // Writes: two ds_write_b128, k-contiguous in the n-rows of Wl.
    {
        const float* Wh = W + h * (INF * OUTF);
        int n0 = (t & 63) * 2;
        int k0 = (t >> 6) * 8;
        float2 v[8];
#pragma unroll
        for (int j = 0; j < 8; ++j)
            v[j] = *(const float2*)(Wh + (k0 + j) * OUTF + n0);
        bf16x8 a0, a1;
#pragma unroll
        for (int j = 0; j < 8; ++j) {
            a0[j] = (short)f2bf(v[j].x);
            a1[j] = (short)f2bf(v[j].y);
        }
        *(bf16x8*)(&Wl[(n0 + 0) * LDSK + k0]) = a0;
        *(bf16x8*)(&Wl[(n0 + 1) * LDSK + k0]) = a1;
    }

    // ---- 3) Pre-barrier: bias loads + A-fragment conversion (no LDS dep) ----
    float bv[2];
#pragma unroll
    for (int nt = 0; nt < 2; ++nt)
        bv[nt] = bias[h * OUTF + ncol + nt * 16 + l16];

    bf16x8 a[4];
#pragma unroll
    for (int kt = 0; kt < 4; ++kt) {
        float vv[8] __attribute__((aligned(16)));
        *(float4*)(&vv[0]) = xv[2 * kt];
        *(float4*)(&vv[4]) = xv[2 * kt + 1];
#pragma unroll
        for (int j = 0; j < 8; ++j) a[kt][j] = (short)f2bf(vv[j]);
    }

    __syncthreads();

    // ---- 4) MFMA: harness-verified B read path (unchanged layout) ----
    // b[j] = B[k=quad*8+kt*32+j][n], k-contiguous in Wl.
    f32x4 acc[2];
#pragma unroll
    for (int nt = 0; nt < 2; ++nt) acc[nt] = (f32x4){0.f, 0.f, 0.f, 0.f};
#pragma unroll
    for (int nt = 0; nt < 2; ++nt) {
        const unsigned short* Wn = &Wl[(ncol + nt * 16 + l16) * LDSK + quad * 8];
#pragma unroll
        for (int kt = 0; kt < 4; ++kt) {
            bf16x8 b = *(const bf16x8*)(Wn + kt * 32);
            acc[nt] = __builtin_amdgcn_mfma_f32_16x16x32_bf16(a[kt], b, acc[nt], 0, 0, 0);
        }
    }

    // ---- Epilogue: C/D layout col=lane&15, row=quad*4+reg (m89-verified) ----
    float* Yg = Y + (g * NPG + mrow) * OUTF + ncol;
#pragma unroll
    for (int nt = 0; nt < 2; ++nt) {
#pragma unroll
        for (int r = 0; r < 4; ++r)
            __builtin_nontemporal_store(acc[nt][r] + bv[nt],
                &Yg[(quad * 4 + r) * OUTF + nt * 16 + l16]);
    }
}

extern "C" void kernel_launch(void* const* d_in, const int* in_sizes, int n_in,
                              void* d_out, int out_size, void* d_ws, size_t ws_size,
                              hipStream_t stream) {
    // setup_inputs order: inputs, n_node, head, kernel, bias
    const float* X    = (const float*)d_in[0];
    const int*   head = (const int*)d_in[2];
    const float* W    = (const float*)d_in[3];
    const float* bias = (const float*)d_in[4];
    float* Y = (float*)d_out;

    mhl_fused_kernel<<<NG, 1024, 0, stream>>>(X, head, W, bias, Y);
}

// Round 4
// 69.895 us; speedup vs baseline: 1.0182x; 1.0182x over previous
//
#include <hip/hip_runtime.h>

// Problem constants (fixed by setup_inputs)
#define NG   256   // graphs
#define NPG  64    // nodes per graph
#define INF  128   // in features (K)
#define OUTF 128   // out features (N)
#define NH   16    // heads

// LDS row stride for Wl[n][k] in bf16 units.
// 136 bf16 = 272 B = 68 dwords: rows stay 16B-aligned (ds_read_b128 ok) and
// the b128 B-fragment read (start bank 4*(l16+quad) % 32) spreads the wave's
// 64 lanes x 4 dwords uniformly at 8 dwords/bank = the conflict-free floor.
#define LDSK 136

typedef __attribute__((ext_vector_type(8))) short bf16x8;  // 8 bf16 = 4 VGPRs
typedef __attribute__((ext_vector_type(4))) float f32x4;   // MFMA accumulator

__device__ __forceinline__ unsigned short f2bf(float f) {
    union { float f; unsigned int i; } c; c.f = f;
    unsigned int r = c.i + 0x7fffu + ((c.i >> 16) & 1u);  // round-to-nearest-even
    return (unsigned short)(r >> 16);
}

// One block per graph (grid 256 = 1 block/CU), 512 threads = 8 waves.
// This is the round-2 structure (best measured: 69.7 us) with one change:
// the A-fragment fp32->bf16 conversion is hoisted ABOVE the barrier (it
// depends only on the X loads issued at instruction 0, not on LDS), so the
// post-barrier critical path is just ds_read_b128 + MFMA + stores.
//
// R3 lesson (1024 threads regressed): occupancy was not the limiter; the
// 16x32 tile doubled X duplication and lengthened the barrier drain.
__global__ __launch_bounds__(512) void mhl_fused_kernel(
    const float* __restrict__ X,     // [NG*NPG][INF] fp32
    const int*   __restrict__ head,  // [NG]
    const float* __restrict__ W,     // [NH][INF][OUTF] fp32
    const float* __restrict__ bias,  // [NH][OUTF] fp32
    float*       __restrict__ Y)     // [NG*NPG][OUTF] fp32
{
    __shared__ __align__(16) unsigned short Wl[OUTF * LDSK];  // 34816 B

    int g = (int)blockIdx.x;
    int t = (int)threadIdx.x;
    int wave = t >> 6, lane = t & 63;
    int quad = lane >> 4, l16 = lane & 15;
    int mrow = (wave & 3) * 16;    // row tile within graph
    int ncol = (wave >> 2) * 64;   // column half

    // ---- 1) Issue X loads up front (in flight during staging + barrier) ----
    const float* Xg = X + (g * NPG + mrow + l16) * INF + quad * 8;
    float4 xv[8];
#pragma unroll
    for (int kt = 0; kt < 4; ++kt) {
        xv[2 * kt]     = *(const float4*)(Xg + kt * 32);
        xv[2 * kt + 1] = *(const float4*)(Xg + kt * 32 + 4);
    }

    int h = head[g];  // uniform -> s_load

    // ---- 2) Stage W[h] -> Wl[n][k] bf16, vectorized ----
    // idx in [0,1024): column pair n0=2*(idx&63), k-chunk k0=8*(idx>>6).
    // Loads: j=0..7, W[k0+j][n0..n0+1] -- each instruction covers one full
    // 512 B k-row across the wave's 64 lanes (fully coalesced).
    // Writes: two ds_write_b128, k-contiguous in the n-rows of Wl.
    {
        const float* Wh = W + h * (INF * OUTF);
#pragma unroll
        for (int c = 0; c < 2; ++c) {
            int idx = c * 512 + t;
            int n0 = (idx & 63) * 2;
            int k0 = (idx >> 6) * 8;
            float2 v[8];
#pragma unroll
            for (int j = 0; j < 8; ++j)
                v[j] = *(const float2*)(Wh + (k0 + j) * OUTF + n0);
            bf16x8 a0, a1;
#pragma unroll
            for (int j = 0; j < 8; ++j) {
                a0[j] = (short)f2bf(v[j].x);
                a1[j] = (short)f2bf(v[j].y);
            }
            *(bf16x8*)(&Wl[(n0 + 0) * LDSK + k0]) = a0;
            *(bf16x8*)(&Wl[(n0 + 1) * LDSK + k0]) = a1;
        }
    }

    // ---- 3) Pre-barrier: bias loads + A-fragment conversion (no LDS dep) ----
    float bv[4];
#pragma unroll
    for (int nt = 0; nt < 4; ++nt)
        bv[nt] = bias[h * OUTF + ncol + nt * 16 + l16];

    bf16x8 a[4];
#pragma unroll
    for (int kt = 0; kt < 4; ++kt) {
        float vv[8] __attribute__((aligned(16)));
        *(float4*)(&vv[0]) = xv[2 * kt];
        *(float4*)(&vv[4]) = xv[2 * kt + 1];
#pragma unroll
        for (int j = 0; j < 8; ++j) a[kt][j] = (short)f2bf(vv[j]);
    }

    __syncthreads();

    // ---- 4) MFMA: harness-verified B read path (unchanged layout) ----
    // b[j] = B[k=quad*8+kt*32+j][n], k-contiguous in Wl.
    f32x4 acc[4];
#pragma unroll
    for (int nt = 0; nt < 4; ++nt) acc[nt] = (f32x4){0.f, 0.f, 0.f, 0.f};
#pragma unroll
    for (int nt = 0; nt < 4; ++nt) {
        const unsigned short* Wn = &Wl[(ncol + nt * 16 + l16) * LDSK + quad * 8];
#pragma unroll
        for (int kt = 0; kt < 4; ++kt) {
            bf16x8 b = *(const bf16x8*)(Wn + kt * 32);
            acc[nt] = __builtin_amdgcn_mfma_f32_16x16x32_bf16(a[kt], b, acc[nt], 0, 0, 0);
        }
    }

    // ---- Epilogue: C/D layout col=lane&15, row=quad*4+reg (m89-verified) ----
    float* Yg = Y + (g * NPG + mrow) * OUTF + ncol;
#pragma unroll
    for (int nt = 0; nt < 4; ++nt) {
#pragma unroll
        for (int r = 0; r < 4; ++r)
            __builtin_nontemporal_store(acc[nt][r] + bv[nt],
                &Yg[(quad * 4 + r) * OUTF + nt * 16 + l16]);
    }
}

extern "C" void kernel_launch(void* const* d_in, const int* in_sizes, int n_in,
                              void* d_out, int out_size, void* d_ws, size_t ws_size,
                              hipStream_t stream) {
    // setup_inputs order: inputs, n_node, head, kernel, bias
    const float* X    = (const float*)d_in[0];
    const int*   head = (const int*)d_in[2];
    const float* W    = (const float*)d_in[3];
    const float* bias = (const float*)d_in[4];
    float* Y = (float*)d_out;

    mhl_fused_kernel<<<NG, 512, 0, stream>>>(X, head, W, bias, Y);
}